// Round 7
// baseline (299.601 us; speedup 1.0000x reference)
//
#include <hip/hip_runtime.h>

// MultiHeadAttention B=2,T=2048,D=1024,H=16,hd=64 fp32.
// R7: flash with NO LDS K/V and NO barriers — MFMA fragments loaded directly
// from global (L1/L2-resident via XCD swizzle), K register-double-buffered,
// Q pre-scaled by log2e/8 in gemm_qkv so p = exp2(s) raw (offset cancels in
// O/l), v_perm packing, P round-trip stride 76. GEMMs/split as R5/R6.

typedef __attribute__((ext_vector_type(8))) short bf16x8;
typedef __attribute__((ext_vector_type(4))) float f32x4;

#define E22 ((size_t)1 << 22)
#define E20 ((size_t)1 << 20)

__device__ __forceinline__ unsigned short f2bf(float x) {
    unsigned int u = __float_as_uint(x);
    u += 0x7fffu + ((u >> 16) & 1u);
    return (unsigned short)(u >> 16);
}
__device__ __forceinline__ unsigned int pk2bf(float a, float b) {
    // [b_hi16 | a_hi16] in one v_perm_b32
    return __builtin_amdgcn_perm(__float_as_uint(a), __float_as_uint(b), 0x03020706u);
}
__device__ __forceinline__ void gl16(const void* g, void* l) {
    __builtin_amdgcn_global_load_lds(
        (const __attribute__((address_space(1))) void*)g,
        (__attribute__((address_space(3))) void*)l, 16, 0, 0);
}
__device__ __forceinline__ f32x4 mfma16(bf16x8 a, bf16x8 b, f32x4 c) {
    return __builtin_amdgcn_mfma_f32_16x16x32_bf16(a, b, c, 0, 0, 0);
}

// ---------------------------------------------------------------------------
// split: fp32 -> bf16. q/k/v -> [0,3*E22); Wq,Wk,Wv -> Wcat[3072,1024] at
// 3*E22; Wo -> 3*E22+3*E20. 4M threads, one float4 each.
// ---------------------------------------------------------------------------
__global__ __launch_bounds__(256)
void split_all(const float* __restrict__ q, const float* __restrict__ k,
               const float* __restrict__ v, const float* __restrict__ wq,
               const float* __restrict__ wk, const float* __restrict__ wv,
               const float* __restrict__ wo, unsigned short* __restrict__ ws)
{
    const size_t t = (size_t)blockIdx.x * 256 + threadIdx.x;
    const size_t e = t * 4;
    const float* src; unsigned short* dst; size_t off;
    if (e < 3 * E22) {
        const unsigned int which = (unsigned int)(e >> 22);
        src = which == 0 ? q : (which == 1 ? k : v);
        off = e & (E22 - 1);
        dst = ws + (size_t)which * E22;
    } else {
        const size_t e2 = e - 3 * E22;
        const unsigned int which = (unsigned int)(e2 >> 20);
        off = e2 & (E20 - 1);
        src = which == 0 ? wq : (which == 1 ? wk : (which == 2 ? wv : wo));
        dst = ws + 3 * E22 + (size_t)which * E20;
    }
    const float4 xv = *(const float4*)(src + off);
    ushort4 h4;
    h4.x = f2bf(xv.x); h4.y = f2bf(xv.y); h4.z = f2bf(xv.z); h4.w = f2bf(xv.w);
    *(ushort4*)(dst + off) = h4;
}

// ---------------------------------------------------------------------------
// Fused QKV bf16 GEMM. Flat grid 768, XCD swizzle. Q output (which==0) is
// PRE-SCALED by log2e/8 so flash's softmax is a bare exp2.
// ---------------------------------------------------------------------------
__global__ __launch_bounds__(256)
void gemm_qkv(const unsigned short* __restrict__ Xall,
              const unsigned short* __restrict__ Wcat,
              const float* __restrict__ bq, const float* __restrict__ bk,
              const float* __restrict__ bv, unsigned short* __restrict__ Qhp,
              unsigned short* __restrict__ Khp, unsigned short* __restrict__ Vtp)
{
    __shared__ unsigned short Xs[4096], Ws[4096];
    const int tid = threadIdx.x;
    const int w = tid >> 6, ln = tid & 63;
    const int quad = ln >> 4, L = ln & 15;
    const int wy = w >> 1, wx = w & 1;

    const int bid = blockIdx.x;
    const int xcd = bid & 7, j = bid >> 3;
    const int gg = xcd * 12 + (j >> 3);
    const int which = gg >> 5, m_i = gg & 31, n_i = j & 7;
    const int m0 = m_i * 128;

    const unsigned short* X = Xall + (size_t)which * E22;
    const unsigned short* W = Wcat + ((size_t)which * 1024 + n_i * 128) * 1024;
    const float* bp = which == 0 ? bq : (which == 1 ? bk : bv);
    unsigned short* outp = which == 0 ? Qhp : (which == 1 ? Khp : Vtp);
    const float qscale = which == 0 ? 0.18033688011f : 1.0f;   // log2(e)/8

    f32x4 acc[4][4];
#pragma unroll
    for (int i = 0; i < 4; ++i)
#pragma unroll
        for (int jj = 0; jj < 4; ++jj) { f32x4 z = {0.f,0.f,0.f,0.f}; acc[i][jj] = z; }

    for (int k0 = 0; k0 < 1024; k0 += 32) {
        __syncthreads();
#pragma unroll
        for (int i = 0; i < 2; ++i) {
            const int ci  = i * 64 + ln;
            const int row = w * 32 + (ci >> 2);
            const int gc  = (ci & 3) ^ ((row >> 1) & 3);
            const size_t goff = (size_t)row * 1024 + k0 + gc * 8;
            const int lb = w * 2048 + i * 1024;
            gl16(X + (size_t)m0 * 1024 + goff, (char*)Xs + lb);
            gl16(W + goff, (char*)Ws + lb);
        }
        __syncthreads();

        bf16x8 ah[4], bh[4];
#pragma unroll
        for (int mt = 0; mt < 4; ++mt) {
            const int row = wy * 64 + mt * 16 + L;
            ah[mt] = *(const bf16x8*)(Xs + row * 32 + ((quad ^ ((row >> 1) & 3)) * 8));
        }
#pragma unroll
        for (int nt = 0; nt < 4; ++nt) {
            const int row = wx * 64 + nt * 16 + L;
            bh[nt] = *(const bf16x8*)(Ws + row * 32 + ((quad ^ ((row >> 1) & 3)) * 8));
        }
#pragma unroll
        for (int mt = 0; mt < 4; ++mt)
#pragma unroll
            for (int nt = 0; nt < 4; ++nt)
                acc[mt][nt] = mfma16(ah[mt], bh[nt], acc[mt][nt]);
    }

#pragma unroll
    for (int mt = 0; mt < 4; ++mt)
#pragma unroll
        for (int nt = 0; nt < 4; ++nt) {
            const int gm0 = m0 + wy * 64 + mt * 16 + quad * 4;
            const int bn  = n_i * 128 + wx * 64 + nt * 16 + L;
            const float bvv = bp[bn];
            const int hh = bn >> 6, dd = bn & 63;
            if (which < 2) {
#pragma unroll
                for (int r = 0; r < 4; ++r) {
                    const int gm = gm0 + r;
                    const int bb = gm >> 11, tt = gm & 2047;
                    outp[((size_t)(bb * 16 + hh) * 2048 + tt) * 64 + dd] =
                        f2bf((acc[mt][nt][r] + bvv) * qscale);
                }
            } else {
                const int bb = gm0 >> 11, t0 = gm0 & 2047;
                ushort4 pk;
                pk.x = f2bf(acc[mt][nt][0] + bvv);
                pk.y = f2bf(acc[mt][nt][1] + bvv);
                pk.z = f2bf(acc[mt][nt][2] + bvv);
                pk.w = f2bf(acc[mt][nt][3] + bvv);
                *(ushort4*)(outp + ((size_t)(bb * 16 + hh) * 64 + dd) * 2048 + t0) = pk;
            }
        }
}

// ---------------------------------------------------------------------------
// Wo GEMM (unchanged). 128x64 tile, flat grid 512, XCD swizzle.
// ---------------------------------------------------------------------------
__global__ __launch_bounds__(256)
void gemm_out(const unsigned short* __restrict__ X, const unsigned short* __restrict__ W,
              const float* __restrict__ bias, float* __restrict__ outp)
{
    __shared__ unsigned short Xs[4096], Ws[2048];
    const int tid = threadIdx.x;
    const int w = tid >> 6, ln = tid & 63;
    const int quad = ln >> 4, L = ln & 15;

    const int bid = blockIdx.x;
    const int xcd = bid & 7, j = bid >> 3;
    const int m0 = (xcd * 4 + (j >> 4)) * 128;
    const int n0 = (j & 15) * 64;

    f32x4 acc[2][4];
#pragma unroll
    for (int i = 0; i < 2; ++i)
#pragma unroll
        for (int jj = 0; jj < 4; ++jj) { f32x4 z = {0.f,0.f,0.f,0.f}; acc[i][jj] = z; }

    for (int k0 = 0; k0 < 1024; k0 += 32) {
        __syncthreads();
#pragma unroll
        for (int i = 0; i < 2; ++i) {
            const int ci  = i * 64 + ln;
            const int row = w * 32 + (ci >> 2);
            const int gc  = (ci & 3) ^ ((row >> 1) & 3);
            const size_t gx = (size_t)(m0 + row) * 1024 + k0 + gc * 8;
            gl16(X + gx, (char*)Xs + w * 2048 + i * 1024);
        }
        {
            const int row = w * 16 + (ln >> 2);
            const int gc  = (ln & 3) ^ ((row >> 1) & 3);
            const size_t gw = (size_t)(n0 + row) * 1024 + k0 + gc * 8;
            gl16(W + gw, (char*)Ws + w * 1024);
        }
        __syncthreads();

        bf16x8 ah[2], bh[4];
#pragma unroll
        for (int mt = 0; mt < 2; ++mt) {
            const int row = w * 32 + mt * 16 + L;
            ah[mt] = *(const bf16x8*)(Xs + row * 32 + ((quad ^ ((row >> 1) & 3)) * 8));
        }
#pragma unroll
        for (int nt = 0; nt < 4; ++nt) {
            const int row = nt * 16 + L;
            bh[nt] = *(const bf16x8*)(Ws + row * 32 + ((quad ^ ((row >> 1) & 3)) * 8));
        }
#pragma unroll
        for (int mt = 0; mt < 2; ++mt)
#pragma unroll
            for (int nt = 0; nt < 4; ++nt)
                acc[mt][nt] = mfma16(ah[mt], bh[nt], acc[mt][nt]);
    }

#pragma unroll
    for (int mt = 0; mt < 2; ++mt)
#pragma unroll
        for (int nt = 0; nt < 4; ++nt) {
            const int gm0 = m0 + w * 32 + mt * 16 + quad * 4;
            const int gn  = n0 + nt * 16 + L;
            const float bvv = bias[gn];
#pragma unroll
            for (int r = 0; r < 4; ++r)
                outp[(size_t)(gm0 + r) * 1024 + gn] = acc[mt][nt][r] + bvv;
        }
}

// ---------------------------------------------------------------------------
// Flash R7: no LDS K/V, no barriers. Flat grid 512: xcd=bid&7, j=bid>>3,
// bh=xcd*4+(j&3), qt=j>>2 (q-tile 128, wave = 32 q-rows, fully independent).
// K/V A-frags loaded straight from global as dwordx4 (L1 shares across the
// 4 waves; L2 XCD-local). K double-buffered in regs; V just-in-time with the
// exp phase as cover. S^T = K Q^T, O^T = V^T P^T; P round-trip through
// per-wave LDS (stride 76). p = exp2(s) (Q pre-scaled; norm cancels offset).
// ---------------------------------------------------------------------------
__global__ __launch_bounds__(256, 2)
void flash(const unsigned short* __restrict__ Qh, const unsigned short* __restrict__ Kh,
           const unsigned short* __restrict__ Vt, unsigned short* __restrict__ A)
{
    __shared__ unsigned short PT[4 * 32 * 76];
    const int tid = threadIdx.x;
    const int w = tid >> 6, ln = tid & 63;
    const int quad = ln >> 4, L = ln & 15;

    const int bid = blockIdx.x;
    const int xcd = bid & 7, j = bid >> 3;
    const int bh_i = xcd * 4 + (j & 3);
    const int qt = j >> 2;
    const int b = bh_i >> 4, h = bh_i & 15;

    const unsigned short* Qb = Qh + ((size_t)bh_i * 2048 + qt * 128 + w * 32) * 64;
    const unsigned short* Kb = Kh + (size_t)bh_i * 2048 * 64;
    const unsigned short* Vb = Vt + (size_t)bh_i * 64 * 2048;

    // Q as B-operand: B[n=q=nt*16+L][k=d]
    bf16x8 bq[2][2];
#pragma unroll
    for (int nt = 0; nt < 2; ++nt)
#pragma unroll
        for (int kc = 0; kc < 2; ++kc)
            bq[nt][kc] = *(const bf16x8*)(Qb + (nt * 16 + L) * 64 + kc * 32 + quad * 8);

    // loop-invariant lane offsets (elements)
    int koff[4][2], voff[4][2];
#pragma unroll
    for (int mt = 0; mt < 4; ++mt)
#pragma unroll
        for (int kc = 0; kc < 2; ++kc) {
            koff[mt][kc] = (mt * 16 + L) * 64 + kc * 32 + quad * 8;
            voff[mt][kc] = (mt * 16 + L) * 2048 + kc * 32 + quad * 8;
        }

    const short one_bf = (short)0x3F80;
    bf16x8 bone = {one_bf, one_bf, one_bf, one_bf, one_bf, one_bf, one_bf, one_bf};

    f32x4 o[4][2];
    f32x4 lacc[2];
#pragma unroll
    for (int mt = 0; mt < 4; ++mt)
#pragma unroll
        for (int nt = 0; nt < 2; ++nt) { f32x4 z = {0.f,0.f,0.f,0.f}; o[mt][nt] = z; }
#pragma unroll
    for (int nt = 0; nt < 2; ++nt) { f32x4 z = {0.f,0.f,0.f,0.f}; lacc[nt] = z; }

    unsigned short* Pw = PT + w * 32 * 76;

    // K double buffer: preload kt=0
    bf16x8 ak[2][4][2], av[4][2];
#pragma unroll
    for (int mt = 0; mt < 4; ++mt)
#pragma unroll
        for (int kc = 0; kc < 2; ++kc)
            ak[0][mt][kc] = *(const bf16x8*)(Kb + koff[mt][kc]);

#pragma unroll 2
    for (int kt = 0; kt < 32; ++kt) {
        const int cur = kt & 1;
        const unsigned short* Kn = Kb + ((kt + 1) & 31) * 4096;  // wrap: harmless refetch
        const unsigned short* Vk = Vb + kt * 64;

        // prefetch K(kt+1); load V(kt) — exp phase covers its latency
#pragma unroll
        for (int mt = 0; mt < 4; ++mt)
#pragma unroll
            for (int kc = 0; kc < 2; ++kc) {
                ak[cur ^ 1][mt][kc] = *(const bf16x8*)(Kn + koff[mt][kc]);
                av[mt][kc]          = *(const bf16x8*)(Vk + voff[mt][kc]);
            }

        // S^T = K Q^T : col(n)=q=L, row(m)=key=quad*4+r
        f32x4 s[4][2];
#pragma unroll
        for (int mt = 0; mt < 4; ++mt)
#pragma unroll
            for (int nt = 0; nt < 2; ++nt) {
                f32x4 z = {0.f,0.f,0.f,0.f};
                z = mfma16(ak[cur][mt][0], bq[nt][0], z);
                z = mfma16(ak[cur][mt][1], bq[nt][1], z);
                s[mt][nt] = z;
            }

        // p = exp2(s); pack 4 consecutive keys -> one b64 LDS write
#pragma unroll
        for (int mt = 0; mt < 4; ++mt)
#pragma unroll
            for (int nt = 0; nt < 2; ++nt) {
                const float p0 = __builtin_amdgcn_exp2f(s[mt][nt][0]);
                const float p1 = __builtin_amdgcn_exp2f(s[mt][nt][1]);
                const float p2 = __builtin_amdgcn_exp2f(s[mt][nt][2]);
                const float p3 = __builtin_amdgcn_exp2f(s[mt][nt][3]);
                uint2 pk2;
                pk2.x = pk2bf(p0, p1);
                pk2.y = pk2bf(p2, p3);
                *(uint2*)(Pw + (nt * 16 + L) * 76 + mt * 16 + quad * 4) = pk2;
            }
        asm volatile("s_waitcnt lgkmcnt(0)" ::: "memory");   // wave-local P vis

        // O^T += V^T P^T ; l += 1·P^T
        bf16x8 pb[2][2];
#pragma unroll
        for (int nt = 0; nt < 2; ++nt)
#pragma unroll
            for (int kc = 0; kc < 2; ++kc)
                pb[nt][kc] = *(const bf16x8*)(Pw + (nt * 16 + L) * 76 + kc * 32 + quad * 8);

#pragma unroll
        for (int mt = 0; mt < 4; ++mt)
#pragma unroll
            for (int nt = 0; nt < 2; ++nt) {
                o[mt][nt] = mfma16(av[mt][0], pb[nt][0], o[mt][nt]);
                o[mt][nt] = mfma16(av[mt][1], pb[nt][1], o[mt][nt]);
            }
#pragma unroll
        for (int nt = 0; nt < 2; ++nt) {
            lacc[nt] = mfma16(bone, pb[nt][0], lacc[nt]);
            lacc[nt] = mfma16(bone, pb[nt][1], lacc[nt]);
        }
    }

    // epilogue: O^T/l -> bf16 into A [B*T, D]; lane q=nt*16+L, rows d.
#pragma unroll
    for (int nt = 0; nt < 2; ++nt) {
        const float inv = 1.0f / lacc[nt][0];
        const int qrow = b * 2048 + qt * 128 + w * 32 + nt * 16 + L;
#pragma unroll
        for (int mt = 0; mt < 4; ++mt) {
            const int d0 = mt * 16 + quad * 4;
            ushort4 pk;
            pk.x = f2bf(o[mt][nt][0] * inv);
            pk.y = f2bf(o[mt][nt][1] * inv);
            pk.z = f2bf(o[mt][nt][2] * inv);
            pk.w = f2bf(o[mt][nt][3] * inv);
            *(ushort4*)(A + (size_t)qrow * 1024 + h * 64 + d0) = pk;
        }
    }
}

// ---------------------------------------------------------------------------
extern "C" void kernel_launch(void* const* d_in, const int* in_sizes, int n_in,
                              void* d_out, int out_size, void* d_ws, size_t ws_size,
                              hipStream_t stream) {
    const float* q  = (const float*)d_in[0];
    const float* k  = (const float*)d_in[1];
    const float* v  = (const float*)d_in[2];
    const float* Wq = (const float*)d_in[3];
    const float* bq = (const float*)d_in[4];
    const float* Wk = (const float*)d_in[5];
    const float* bk = (const float*)d_in[6];
    const float* Wv = (const float*)d_in[7];
    const float* bv = (const float*)d_in[8];
    const float* Wo = (const float*)d_in[9];
    const float* bo = (const float*)d_in[10];

    unsigned short* W = (unsigned short*)d_ws;
    unsigned short *Xall = W;                      // q,k,v bf16 [3*E22]
    unsigned short *Wcat = W + 3 * E22;            // [3072,1024] bf16
    unsigned short *Wob  = Wcat + 3 * E20;         // [1024,1024] bf16
    unsigned short *Qhp  = W + 4 * E22;            // [B,H,T,64] (pre-scaled)
    unsigned short *Khp  = W + 5 * E22;
    unsigned short *Vtp  = W + 6 * E22;            // [B,H,64,T]
    unsigned short *A    = W;                      // reuse q_b (dead)

    split_all<<<16384, 256, 0, stream>>>(q, k, v, Wq, Wk, Wv, Wo, W);

    gemm_qkv<<<768, 256, 0, stream>>>(Xall, Wcat, bq, bk, bv, Qhp, Khp, Vtp);

    flash<<<512, 256, 0, stream>>>(Qhp, Khp, Vtp, A);

    gemm_out<<<512, 256, 0, stream>>>(A, Wob, bo, (float*)d_out);
}

// Round 8
// 224.363 us; speedup vs baseline: 1.3353x; 1.3353x over previous
//
#include <hip/hip_runtime.h>

// MultiHeadAttention B=2,T=2048,D=1024,H=16,hd=64 fp32.
// R8: flash = R6 LDS-staged structure, but 4 waves split 2(q-half)x2(key-half)
// so K/V LDS frag reads are 2x (not 4x) duplicated; cross-wave O reduction
// through retired K/V LDS at the end. Pre-scaled Q (bare exp2) + v_perm pack
// kept from R7. GEMMs/split unchanged.

typedef __attribute__((ext_vector_type(8))) short bf16x8;
typedef __attribute__((ext_vector_type(4))) float f32x4;

#define E22 ((size_t)1 << 22)
#define E20 ((size_t)1 << 20)

__device__ __forceinline__ unsigned short f2bf(float x) {
    unsigned int u = __float_as_uint(x);
    u += 0x7fffu + ((u >> 16) & 1u);
    return (unsigned short)(u >> 16);
}
__device__ __forceinline__ unsigned int pk2bf(float a, float b) {
    // [b_hi16 | a_hi16] in one v_perm_b32
    return __builtin_amdgcn_perm(__float_as_uint(a), __float_as_uint(b), 0x03020706u);
}
__device__ __forceinline__ void gl16(const void* g, void* l) {
    __builtin_amdgcn_global_load_lds(
        (const __attribute__((address_space(1))) void*)g,
        (__attribute__((address_space(3))) void*)l, 16, 0, 0);
}
__device__ __forceinline__ f32x4 mfma16(bf16x8 a, bf16x8 b, f32x4 c) {
    return __builtin_amdgcn_mfma_f32_16x16x32_bf16(a, b, c, 0, 0, 0);
}

// ---------------------------------------------------------------------------
// split: fp32 -> bf16. q/k/v -> [0,3*E22); Wq,Wk,Wv -> Wcat[3072,1024] at
// 3*E22; Wo -> 3*E22+3*E20. 4M threads, one float4 each.
// ---------------------------------------------------------------------------
__global__ __launch_bounds__(256)
void split_all(const float* __restrict__ q, const float* __restrict__ k,
               const float* __restrict__ v, const float* __restrict__ wq,
               const float* __restrict__ wk, const float* __restrict__ wv,
               const float* __restrict__ wo, unsigned short* __restrict__ ws)
{
    const size_t t = (size_t)blockIdx.x * 256 + threadIdx.x;
    const size_t e = t * 4;
    const float* src; unsigned short* dst; size_t off;
    if (e < 3 * E22) {
        const unsigned int which = (unsigned int)(e >> 22);
        src = which == 0 ? q : (which == 1 ? k : v);
        off = e & (E22 - 1);
        dst = ws + (size_t)which * E22;
    } else {
        const size_t e2 = e - 3 * E22;
        const unsigned int which = (unsigned int)(e2 >> 20);
        off = e2 & (E20 - 1);
        src = which == 0 ? wq : (which == 1 ? wk : (which == 2 ? wv : wo));
        dst = ws + 3 * E22 + (size_t)which * E20;
    }
    const float4 xv = *(const float4*)(src + off);
    ushort4 h4;
    h4.x = f2bf(xv.x); h4.y = f2bf(xv.y); h4.z = f2bf(xv.z); h4.w = f2bf(xv.w);
    *(ushort4*)(dst + off) = h4;
}

// ---------------------------------------------------------------------------
// Fused QKV bf16 GEMM. Flat grid 768, XCD swizzle. Q output (which==0) is
// PRE-SCALED by log2e/8 so flash's softmax is a bare exp2.
// ---------------------------------------------------------------------------
__global__ __launch_bounds__(256)
void gemm_qkv(const unsigned short* __restrict__ Xall,
              const unsigned short* __restrict__ Wcat,
              const float* __restrict__ bq, const float* __restrict__ bk,
              const float* __restrict__ bv, unsigned short* __restrict__ Qhp,
              unsigned short* __restrict__ Khp, unsigned short* __restrict__ Vtp)
{
    __shared__ unsigned short Xs[4096], Ws[4096];
    const int tid = threadIdx.x;
    const int w = tid >> 6, ln = tid & 63;
    const int quad = ln >> 4, L = ln & 15;
    const int wy = w >> 1, wx = w & 1;

    const int bid = blockIdx.x;
    const int xcd = bid & 7, j = bid >> 3;
    const int gg = xcd * 12 + (j >> 3);
    const int which = gg >> 5, m_i = gg & 31, n_i = j & 7;
    const int m0 = m_i * 128;

    const unsigned short* X = Xall + (size_t)which * E22;
    const unsigned short* W = Wcat + ((size_t)which * 1024 + n_i * 128) * 1024;
    const float* bp = which == 0 ? bq : (which == 1 ? bk : bv);
    unsigned short* outp = which == 0 ? Qhp : (which == 1 ? Khp : Vtp);
    const float qscale = which == 0 ? 0.18033688011f : 1.0f;   // log2(e)/8

    f32x4 acc[4][4];
#pragma unroll
    for (int i = 0; i < 4; ++i)
#pragma unroll
        for (int jj = 0; jj < 4; ++jj) { f32x4 z = {0.f,0.f,0.f,0.f}; acc[i][jj] = z; }

    for (int k0 = 0; k0 < 1024; k0 += 32) {
        __syncthreads();
#pragma unroll
        for (int i = 0; i < 2; ++i) {
            const int ci  = i * 64 + ln;
            const int row = w * 32 + (ci >> 2);
            const int gc  = (ci & 3) ^ ((row >> 1) & 3);
            const size_t goff = (size_t)row * 1024 + k0 + gc * 8;
            const int lb = w * 2048 + i * 1024;
            gl16(X + (size_t)m0 * 1024 + goff, (char*)Xs + lb);
            gl16(W + goff, (char*)Ws + lb);
        }
        __syncthreads();

        bf16x8 ah[4], bh[4];
#pragma unroll
        for (int mt = 0; mt < 4; ++mt) {
            const int row = wy * 64 + mt * 16 + L;
            ah[mt] = *(const bf16x8*)(Xs + row * 32 + ((quad ^ ((row >> 1) & 3)) * 8));
        }
#pragma unroll
        for (int nt = 0; nt < 4; ++nt) {
            const int row = wx * 64 + nt * 16 + L;
            bh[nt] = *(const bf16x8*)(Ws + row * 32 + ((quad ^ ((row >> 1) & 3)) * 8));
        }
#pragma unroll
        for (int mt = 0; mt < 4; ++mt)
#pragma unroll
            for (int nt = 0; nt < 4; ++nt)
                acc[mt][nt] = mfma16(ah[mt], bh[nt], acc[mt][nt]);
    }

#pragma unroll
    for (int mt = 0; mt < 4; ++mt)
#pragma unroll
        for (int nt = 0; nt < 4; ++nt) {
            const int gm0 = m0 + wy * 64 + mt * 16 + quad * 4;
            const int bn  = n_i * 128 + wx * 64 + nt * 16 + L;
            const float bvv = bp[bn];
            const int hh = bn >> 6, dd = bn & 63;
            if (which < 2) {
#pragma unroll
                for (int r = 0; r < 4; ++r) {
                    const int gm = gm0 + r;
                    const int bb = gm >> 11, tt = gm & 2047;
                    outp[((size_t)(bb * 16 + hh) * 2048 + tt) * 64 + dd] =
                        f2bf((acc[mt][nt][r] + bvv) * qscale);
                }
            } else {
                const int bb = gm0 >> 11, t0 = gm0 & 2047;
                ushort4 pk;
                pk.x = f2bf(acc[mt][nt][0] + bvv);
                pk.y = f2bf(acc[mt][nt][1] + bvv);
                pk.z = f2bf(acc[mt][nt][2] + bvv);
                pk.w = f2bf(acc[mt][nt][3] + bvv);
                *(ushort4*)(outp + ((size_t)(bb * 16 + hh) * 64 + dd) * 2048 + t0) = pk;
            }
        }
}

// ---------------------------------------------------------------------------
// Wo GEMM (unchanged). 128x64 tile, flat grid 512, XCD swizzle.
// ---------------------------------------------------------------------------
__global__ __launch_bounds__(256)
void gemm_out(const unsigned short* __restrict__ X, const unsigned short* __restrict__ W,
              const float* __restrict__ bias, float* __restrict__ outp)
{
    __shared__ unsigned short Xs[4096], Ws[2048];
    const int tid = threadIdx.x;
    const int w = tid >> 6, ln = tid & 63;
    const int quad = ln >> 4, L = ln & 15;

    const int bid = blockIdx.x;
    const int xcd = bid & 7, j = bid >> 3;
    const int m0 = (xcd * 4 + (j >> 4)) * 128;
    const int n0 = (j & 15) * 64;

    f32x4 acc[2][4];
#pragma unroll
    for (int i = 0; i < 2; ++i)
#pragma unroll
        for (int jj = 0; jj < 4; ++jj) { f32x4 z = {0.f,0.f,0.f,0.f}; acc[i][jj] = z; }

    for (int k0 = 0; k0 < 1024; k0 += 32) {
        __syncthreads();
#pragma unroll
        for (int i = 0; i < 2; ++i) {
            const int ci  = i * 64 + ln;
            const int row = w * 32 + (ci >> 2);
            const int gc  = (ci & 3) ^ ((row >> 1) & 3);
            const size_t gx = (size_t)(m0 + row) * 1024 + k0 + gc * 8;
            gl16(X + gx, (char*)Xs + w * 2048 + i * 1024);
        }
        {
            const int row = w * 16 + (ln >> 2);
            const int gc  = (ln & 3) ^ ((row >> 1) & 3);
            const size_t gw = (size_t)(n0 + row) * 1024 + k0 + gc * 8;
            gl16(W + gw, (char*)Ws + w * 1024);
        }
        __syncthreads();

        bf16x8 ah[2], bh[4];
#pragma unroll
        for (int mt = 0; mt < 2; ++mt) {
            const int row = w * 32 + mt * 16 + L;
            ah[mt] = *(const bf16x8*)(Xs + row * 32 + ((quad ^ ((row >> 1) & 3)) * 8));
        }
#pragma unroll
        for (int nt = 0; nt < 4; ++nt) {
            const int row = nt * 16 + L;
            bh[nt] = *(const bf16x8*)(Ws + row * 32 + ((quad ^ ((row >> 1) & 3)) * 8));
        }
#pragma unroll
        for (int mt = 0; mt < 2; ++mt)
#pragma unroll
            for (int nt = 0; nt < 4; ++nt)
                acc[mt][nt] = mfma16(ah[mt], bh[nt], acc[mt][nt]);
    }

#pragma unroll
    for (int mt = 0; mt < 2; ++mt)
#pragma unroll
        for (int nt = 0; nt < 4; ++nt) {
            const int gm0 = m0 + w * 32 + mt * 16 + quad * 4;
            const int gn  = n0 + nt * 16 + L;
            const float bvv = bias[gn];
#pragma unroll
            for (int r = 0; r < 4; ++r)
                outp[(size_t)(gm0 + r) * 1024 + gn] = acc[mt][nt][r] + bvv;
        }
}

// ---------------------------------------------------------------------------
// Flash R8. Flat grid 512 (256 thr): xcd=bid&7, j=bid>>3, bh=xcd*4+(j&3),
// qt=j>>2 (q-tile 128). Wave (wq,wk) owns q-half wq (64 rows) x key-half wk
// (32 keys of each 64-key tile). S^T = K Q^T, O^T = V^T P^T. P per-wave LDS,
// stride 72 (16B-aligned). K/V double-buffered (1 barrier/iter). Partial O/l
// over key-halves reduced through retired K/V LDS at the end.
// ---------------------------------------------------------------------------
__global__ __launch_bounds__(256, 2)
void flash(const unsigned short* __restrict__ Qh, const unsigned short* __restrict__ Kh,
           const unsigned short* __restrict__ Vt, unsigned short* __restrict__ A)
{
    __shared__ unsigned short KVs[16384];        // K:[buf*4096], V:[8192+buf*4096]
    __shared__ unsigned short PT[4 * 64 * 72];   // per-wave P [q=64][key=32] str 72
    const int tid = threadIdx.x;
    const int w = tid >> 6, ln = tid & 63;
    const int quad = ln >> 4, L = ln & 15;
    const int wq = w & 1, wk = w >> 1;

    const int bid = blockIdx.x;
    const int xcd = bid & 7, j = bid >> 3;
    const int bh_i = xcd * 4 + (j & 3);
    const int qt = j >> 2;
    const int b = bh_i >> 4, h = bh_i & 15;

    const unsigned short* Qb = Qh + ((size_t)bh_i * 2048 + qt * 128 + wq * 64) * 64;
    const unsigned short* Kb = Kh + (size_t)bh_i * 2048 * 64;
    const unsigned short* Vb = Vt + (size_t)bh_i * 64 * 2048;

    // Q as B-operand: B[n=q=nt*16+L][k=d]
    bf16x8 bq[4][2];
#pragma unroll
    for (int nt = 0; nt < 4; ++nt)
#pragma unroll
        for (int kc = 0; kc < 2; ++kc)
            bq[nt][kc] = *(const bf16x8*)(Qb + (nt * 16 + L) * 64 + kc * 32 + quad * 8);

    const short one_bf = (short)0x3F80;
    bf16x8 bone = {one_bf, one_bf, one_bf, one_bf, one_bf, one_bf, one_bf, one_bf};

    f32x4 o[4][4];        // O^T partial: [mtd over d][nt over q]
    f32x4 lacc[4];
#pragma unroll
    for (int mtd = 0; mtd < 4; ++mtd)
#pragma unroll
        for (int nt = 0; nt < 4; ++nt) { f32x4 z = {0.f,0.f,0.f,0.f}; o[mtd][nt] = z; }
#pragma unroll
    for (int nt = 0; nt < 4; ++nt) { f32x4 z = {0.f,0.f,0.f,0.f}; lacc[nt] = z; }

    unsigned short* Pw = PT + w * 64 * 72;

    // staging (identical to R6): seg = w*2+i over 8 segs of 1KB per tile
    const int ci0 = (w * 2 + 0) * 64 + ln, ci1 = (w * 2 + 1) * 64 + ln;
    const int rr0 = ci0 >> 3, rr1 = ci1 >> 3;
    const int gc0 = (ci0 & 7) ^ (rr0 & 7), gc1 = (ci1 & 7) ^ (rr1 & 7);

#define STAGE(kt_, buf_)                                                        \
    do {                                                                        \
        gl16(Kb + (size_t)((kt_) * 64 + rr0) * 64 + gc0 * 8,                    \
             (char*)KVs + (buf_) * 8192 + (w * 2 + 0) * 1024);                  \
        gl16(Kb + (size_t)((kt_) * 64 + rr1) * 64 + gc1 * 8,                    \
             (char*)KVs + (buf_) * 8192 + (w * 2 + 1) * 1024);                  \
        gl16(Vb + (size_t)rr0 * 2048 + (kt_) * 64 + gc0 * 8,                    \
             (char*)KVs + 16384 + (buf_) * 8192 + (w * 2 + 0) * 1024);          \
        gl16(Vb + (size_t)rr1 * 2048 + (kt_) * 64 + gc1 * 8,                    \
             (char*)KVs + 16384 + (buf_) * 8192 + (w * 2 + 1) * 1024);          \
    } while (0)

    STAGE(0, 0);

    for (int kt = 0; kt < 32; ++kt) {
        const int cur = kt & 1;
        __syncthreads();                       // buf[cur] staged & visible
        if (kt < 31) STAGE(kt + 1, cur ^ 1);   // in flight during compute

        const unsigned short* Ksb = KVs + cur * 4096;
        const unsigned short* Vsb = KVs + 8192 + cur * 4096;

        // K as A-operand: A[m=key=wk*32+mt*16+L][k=d]
        bf16x8 ak[2][2];
#pragma unroll
        for (int mt = 0; mt < 2; ++mt)
#pragma unroll
            for (int kc = 0; kc < 2; ++kc) {
                const int row = wk * 32 + mt * 16 + L;
                ak[mt][kc] = *(const bf16x8*)(Ksb + row * 64 + (((kc * 4 + quad) ^ (L & 7)) * 8));
            }

        // S^T = K Q^T : col(n)=q=L, row(m)=key=quad*4+r (within wave's 32)
        f32x4 s[2][4];
#pragma unroll
        for (int mt = 0; mt < 2; ++mt)
#pragma unroll
            for (int nt = 0; nt < 4; ++nt) {
                f32x4 z = {0.f,0.f,0.f,0.f};
                z = mfma16(ak[mt][0], bq[nt][0], z);
                z = mfma16(ak[mt][1], bq[nt][1], z);
                s[mt][nt] = z;
            }

        // p = exp2(s); pack 4 consecutive local keys -> one b64 LDS write
#pragma unroll
        for (int mt = 0; mt < 2; ++mt)
#pragma unroll
            for (int nt = 0; nt < 4; ++nt) {
                const float p0 = __builtin_amdgcn_exp2f(s[mt][nt][0]);
                const float p1 = __builtin_amdgcn_exp2f(s[mt][nt][1]);
                const float p2 = __builtin_amdgcn_exp2f(s[mt][nt][2]);
                const float p3 = __builtin_amdgcn_exp2f(s[mt][nt][3]);
                uint2 pk2;
                pk2.x = pk2bf(p0, p1);
                pk2.y = pk2bf(p2, p3);
                *(uint2*)(Pw + (nt * 16 + L) * 72 + mt * 16 + quad * 4) = pk2;
            }
        asm volatile("s_waitcnt lgkmcnt(0)" ::: "memory");   // wave-local P vis

        // O^T += V^T P^T over this wave's 32 keys; l partial likewise
        bf16x8 av[4], pb[4];
#pragma unroll
        for (int mtd = 0; mtd < 4; ++mtd) {
            const int row = mtd * 16 + L;
            av[mtd] = *(const bf16x8*)(Vsb + row * 64 + (((wk * 4 + quad) ^ (L & 7)) * 8));
        }
#pragma unroll
        for (int nt = 0; nt < 4; ++nt)
            pb[nt] = *(const bf16x8*)(Pw + (nt * 16 + L) * 72 + quad * 8);

#pragma unroll
        for (int mtd = 0; mtd < 4; ++mtd)
#pragma unroll
            for (int nt = 0; nt < 4; ++nt)
                o[mtd][nt] = mfma16(av[mtd], pb[nt], o[mtd][nt]);
#pragma unroll
        for (int nt = 0; nt < 4; ++nt)
            lacc[nt] = mfma16(bone, pb[nt], lacc[nt]);
    }
#undef STAGE

    // cross-wave reduction over key-halves through retired K/V LDS
    __syncthreads();
    float* Rb = (float*)KVs;               // 8192 floats = 32 KB
    float* Lb = (float*)PT;                // lacc region
    if (wk == 1) {
#pragma unroll
        for (int mtd = 0; mtd < 4; ++mtd)
#pragma unroll
            for (int nt = 0; nt < 4; ++nt)
                *(f32x4*)(Rb + wq * 4096 + (mtd * 4 + nt) * 256 + ln * 4) = o[mtd][nt];
#pragma unroll
        for (int nt = 0; nt < 4; ++nt)
            *(f32x4*)(Lb + wq * 1024 + nt * 256 + ln * 4) = lacc[nt];
    }
    __syncthreads();
    if (wk == 0) {
#pragma unroll
        for (int mtd = 0; mtd < 4; ++mtd)
#pragma unroll
            for (int nt = 0; nt < 4; ++nt)
                o[mtd][nt] += *(const f32x4*)(Rb + wq * 4096 + (mtd * 4 + nt) * 256 + ln * 4);
#pragma unroll
        for (int nt = 0; nt < 4; ++nt)
            lacc[nt] += *(const f32x4*)(Lb + wq * 1024 + nt * 256 + ln * 4);

        // epilogue: O^T/l -> bf16 into A [B*T, D]; lane q=nt*16+L, rows d.
#pragma unroll
        for (int nt = 0; nt < 4; ++nt) {
            const float inv = 1.0f / lacc[nt][0];
            const int qrow = b * 2048 + qt * 128 + wq * 64 + nt * 16 + L;
#pragma unroll
            for (int mtd = 0; mtd < 4; ++mtd) {
                const int d0 = mtd * 16 + quad * 4;
                ushort4 pk;
                pk.x = f2bf(o[mtd][nt][0] * inv);
                pk.y = f2bf(o[mtd][nt][1] * inv);
                pk.z = f2bf(o[mtd][nt][2] * inv);
                pk.w = f2bf(o[mtd][nt][3] * inv);
                *(ushort4*)(A + (size_t)qrow * 1024 + h * 64 + d0) = pk;
            }
        }
    }
}

// ---------------------------------------------------------------------------
extern "C" void kernel_launch(void* const* d_in, const int* in_sizes, int n_in,
                              void* d_out, int out_size, void* d_ws, size_t ws_size,
                              hipStream_t stream) {
    const float* q  = (const float*)d_in[0];
    const float* k  = (const float*)d_in[1];
    const float* v  = (const float*)d_in[2];
    const float* Wq = (const float*)d_in[3];
    const float* bq = (const float*)d_in[4];
    const float* Wk = (const float*)d_in[5];
    const float* bk = (const float*)d_in[6];
    const float* Wv = (const float*)d_in[7];
    const float* bv = (const float*)d_in[8];
    const float* Wo = (const float*)d_in[9];
    const float* bo = (const float*)d_in[10];

    unsigned short* W = (unsigned short*)d_ws;
    unsigned short *Xall = W;                      // q,k,v bf16 [3*E22]
    unsigned short *Wcat = W + 3 * E22;            // [3072,1024] bf16
    unsigned short *Wob  = Wcat + 3 * E20;         // [1024,1024] bf16
    unsigned short *Qhp  = W + 4 * E22;            // [B,H,T,64] (pre-scaled)
    unsigned short *Khp  = W + 5 * E22;
    unsigned short *Vtp  = W + 6 * E22;            // [B,H,64,T]
    unsigned short *A    = W;                      // reuse q_b (dead)

    split_all<<<16384, 256, 0, stream>>>(q, k, v, Wq, Wk, Wv, Wo, W);

    gemm_qkv<<<768, 256, 0, stream>>>(Xall, Wcat, bq, bk, bv, Qhp, Khp, Vtp);

    flash<<<512, 256, 0, stream>>>(Qhp, Khp, Vtp, A);

    gemm_out<<<512, 256, 0, stream>>>(A, Wob, bo, (float*)d_out);
}